// Round 1
// baseline (262.544 us; speedup 1.0000x reference)
//
#include <hip/hip_runtime.h>
#include <math.h>

#define KCONST 0.1f
#define GAMMA_C 1.0f
#define D_DIM 128

#define TM 64
#define TN 64
#define QSTRIDE 65   // float4 stride per kq-row (16 kq rows staged at a time)

// ---------------------------------------------------------------------------
// Kernel A: per-row stats of x: nx2[row] = ||x_row||^2, plus atomically
// accumulated sum_x[128] (column sums) and sum_nx2 (scalar).
// 64 blocks x 256 threads = 256 waves; each wave owns rows gw, gw+256, ...
// ---------------------------------------------------------------------------
__global__ void row_stats(const float* __restrict__ x, float* __restrict__ nx2,
                          float* __restrict__ sum_x, float* __restrict__ sum_nx2,
                          int N) {
  const int lane = threadIdx.x & 63;
  const int wave = threadIdx.x >> 6;
  const int gw = blockIdx.x * 4 + wave;
  const int nw = gridDim.x * 4;
  float c0 = 0.f, c1 = 0.f, s2 = 0.f;
  for (int row = gw; row < N; row += nw) {
    float v0 = x[row * D_DIM + lane];
    float v1 = x[row * D_DIM + 64 + lane];
    c0 += v0;
    c1 += v1;
    float sq = fmaf(v0, v0, v1 * v1);
#pragma unroll
    for (int off = 32; off; off >>= 1) sq += __shfl_down(sq, off);
    if (lane == 0) {
      nx2[row] = sq;
      s2 += sq;
    }
  }
  if (lane == 0) atomicAdd(sum_nx2, s2);
  __shared__ float cs[128];
  if (threadIdx.x < 128) cs[threadIdx.x] = 0.f;
  __syncthreads();
  atomicAdd(&cs[lane], c0);
  atomicAdd(&cs[lane + 64], c1);
  __syncthreads();
  if (threadIdx.x < 128) atomicAdd(&sum_x[threadIdx.x], cs[threadIdx.x]);
}

// ---------------------------------------------------------------------------
// Kernel B: per-column constants of p. One wave per column.
//   c1a  = 1 + ||p||^2
//   np2a = ||p||^2
//   cfia = 1 / (||p|| * sqrt(ssd))      ssd = sum_nx2 + N*np2 - 2*sum_x.p
//   psia = asin(K*(1-np2)/||p||)
// ---------------------------------------------------------------------------
__global__ void col_stats(const float* __restrict__ p, const float* __restrict__ sum_x,
                          const float* __restrict__ sum_nx2,
                          float* __restrict__ c1a, float* __restrict__ np2a,
                          float* __restrict__ cfia, float* __restrict__ psia,
                          int M, int N) {
  const int lane = threadIdx.x & 63;
  const int wave = threadIdx.x >> 6;
  const int j = blockIdx.x * 4 + wave;
  if (j >= M) return;
  float p0 = p[j * D_DIM + lane];
  float p1 = p[j * D_DIM + 64 + lane];
  float np2 = fmaf(p0, p0, p1 * p1);
  float sd = fmaf(p0, sum_x[lane], p1 * sum_x[lane + 64]);
#pragma unroll
  for (int off = 32; off; off >>= 1) {
    np2 += __shfl_down(np2, off);
    sd += __shfl_down(sd, off);
  }
  if (lane == 0) {
    float ssd = *sum_nx2 + (float)N * np2 - 2.f * sd;
    float npn = sqrtf(np2);
    c1a[j] = 1.f + np2;
    np2a[j] = np2;
    cfia[j] = 1.f / (npn * sqrtf(ssd));
    psia[j] = asinf(KCONST * (1.f - np2) / npn);
  }
}

// ---------------------------------------------------------------------------
// Kernel C: fused dot + epilogue + reduction over the [N, M] tile grid.
// 64x64 tile per block, 4x4 micro-tile per thread (strided: col = tx + 16c,
// row = ty + 16r) so wave b-fragment reads are 16 contiguous float4s
// (conflict-free) and a-fragment reads are broadcasts.
// K staged in two 64-deep chunks: LDS = 2 * 16*65 float4 = 33280 B.
// ---------------------------------------------------------------------------
__global__ __launch_bounds__(256, 3) void pair_kernel(
    const float* __restrict__ x, const float* __restrict__ p,
    const int* __restrict__ labels, const float* __restrict__ nx2,
    const float* __restrict__ c1a, const float* __restrict__ np2a,
    const float* __restrict__ cfia, const float* __restrict__ psia,
    float* __restrict__ partials, int M) {
  __shared__ float4 xs4[16 * QSTRIDE];
  __shared__ float4 ps4[16 * QSTRIDE];
  const int tid = threadIdx.x;
  const int row0 = blockIdx.y * TM;
  const int col0 = blockIdx.x * TN;

  const float4* xg = (const float4*)x + row0 * 32;  // 32 quads per row
  const float4* pg = (const float4*)p + col0 * 32;

  const int tx = tid & 15;   // column group
  const int ty = tid >> 4;   // row group (0..15)

  float acc[4][4];
#pragma unroll
  for (int r = 0; r < 4; ++r)
#pragma unroll
    for (int c = 0; c < 4; ++c) acc[r][c] = 0.f;

  for (int kc = 0; kc < 2; ++kc) {
    if (kc) __syncthreads();
    // stage 64 rows x 16 quads for both x and p, k-major transposed
#pragma unroll
    for (int t = 0; t < 4; ++t) {
      int i = tid + t * 256;        // 0..1023
      int r = i >> 4, kq = i & 15;  // r: 0..63, kq: 0..15
      xs4[kq * QSTRIDE + r] = xg[r * 32 + kc * 16 + kq];
      ps4[kq * QSTRIDE + r] = pg[r * 32 + kc * 16 + kq];
    }
    __syncthreads();

#pragma unroll 4
    for (int kq = 0; kq < 16; ++kq) {
      float4 a[4], b[4];
#pragma unroll
      for (int r = 0; r < 4; ++r) a[r] = xs4[kq * QSTRIDE + ty + 16 * r];
#pragma unroll
      for (int c = 0; c < 4; ++c) b[c] = ps4[kq * QSTRIDE + tx + 16 * c];
#pragma unroll
      for (int r = 0; r < 4; ++r)
#pragma unroll
        for (int c = 0; c < 4; ++c) {
          acc[r][c] = fmaf(a[r].x, b[c].x, acc[r][c]);
          acc[r][c] = fmaf(a[r].y, b[c].y, acc[r][c]);
          acc[r][c] = fmaf(a[r].z, b[c].z, acc[r][c]);
          acc[r][c] = fmaf(a[r].w, b[c].w, acc[r][c]);
        }
    }
  }

  // ---- epilogue ----
  float rnx2[4];
  int lab[4];
#pragma unroll
  for (int r = 0; r < 4; ++r) {
    int row = row0 + ty + 16 * r;
    rnx2[r] = nx2[row];
    lab[r] = labels[row];
  }
  float cc1[4], cnp[4], ccf[4], cps[4];
  int ccol[4];
#pragma unroll
  for (int c = 0; c < 4; ++c) {
    int col = col0 + tx + 16 * c;
    ccol[c] = col;
    cc1[c] = c1a[col];
    cnp[c] = np2a[col];
    ccf[c] = cfia[col];
    cps[c] = psia[col];
  }

  float s = 0.f;
#pragma unroll
  for (int r = 0; r < 4; ++r) {
    float r1 = 1.f + rnx2[r];
#pragma unroll
    for (int c = 0; c < 4; ++c) {
      float dot = acc[r][c];
      float num = fmaf(dot, cc1[c], -cnp[c] * r1);
      float t = fmaf(cnp[c], rnx2[r], 1.f) - 2.f * dot;
      float u = num * ccf[c] * rsqrtf(t);
      u = fminf(1.f, fmaxf(-1.f, u));
      float ang = acosf(u) - cps[c];
      float a = fmaxf(0.f, ang);
      float contrib = (ccol[c] == lab[r]) ? a : fmaxf(0.f, GAMMA_C - a);
      s += contrib;
    }
  }

  // block reduction -> one partial per block (plain store, no atomics)
#pragma unroll
  for (int off = 32; off; off >>= 1) s += __shfl_down(s, off);
  __shared__ float wred[4];
  if ((tid & 63) == 0) wred[tid >> 6] = s;
  __syncthreads();
  if (tid == 0)
    partials[blockIdx.y * gridDim.x + blockIdx.x] = wred[0] + wred[1] + wred[2] + wred[3];
}

// ---------------------------------------------------------------------------
// Kernel D: reduce the per-block partials, scale by 1/N, write scalar out.
// ---------------------------------------------------------------------------
__global__ void finalize(const float* __restrict__ partials, float* __restrict__ out,
                         int nparts, float invN) {
  float s = 0.f;
  for (int i = threadIdx.x; i < nparts; i += 256) s += partials[i];
#pragma unroll
  for (int off = 32; off; off >>= 1) s += __shfl_down(s, off);
  __shared__ float w[4];
  if ((threadIdx.x & 63) == 0) w[threadIdx.x >> 6] = s;
  __syncthreads();
  if (threadIdx.x == 0) out[0] = (w[0] + w[1] + w[2] + w[3]) * invN;
}

extern "C" void kernel_launch(void* const* d_in, const int* in_sizes, int n_in,
                              void* d_out, int out_size, void* d_ws, size_t ws_size,
                              hipStream_t stream) {
  const float* x = (const float*)d_in[0];
  const float* p = (const float*)d_in[1];
  const int* labels = (const int*)d_in[2];
  float* out = (float*)d_out;
  const int N = in_sizes[2];          // 16384
  const int M = in_sizes[1] / D_DIM;  // 2048

  float* ws = (float*)d_ws;
  float* sum_x = ws;            // 128
  float* sum_nx2 = ws + 128;    // 1
  float* nx2 = ws + 256;        // N
  float* c1a = nx2 + N;         // M
  float* np2a = c1a + M;        // M
  float* cfia = np2a + M;       // M
  float* psia = cfia + M;       // M
  float* partials = psia + M;   // (N/TM)*(M/TN)

  // zero the atomic accumulators (graph-capture-safe async memset)
  hipMemsetAsync(d_ws, 0, 129 * sizeof(float), stream);

  row_stats<<<64, 256, 0, stream>>>(x, nx2, sum_x, sum_nx2, N);
  col_stats<<<M / 4, 256, 0, stream>>>(p, sum_x, sum_nx2, c1a, np2a, cfia, psia, M, N);

  dim3 grid(M / TN, N / TM);
  pair_kernel<<<grid, 256, 0, stream>>>(x, p, labels, nx2, c1a, np2a, cfia, psia,
                                        partials, M);

  int nparts = (N / TM) * (M / TN);
  finalize<<<1, 256, 0, stream>>>(partials, out, nparts, 1.0f / (float)N);
}

// Round 2
// 230.027 us; speedup vs baseline: 1.1414x; 1.1414x over previous
//
#include <hip/hip_runtime.h>
#include <math.h>

#define KCONST 0.1f
#define GAMMA_C 1.0f
#define D_DIM 128

typedef __attribute__((ext_vector_type(8))) short bf16x8;
typedef __attribute__((ext_vector_type(4))) float f32x4;

__device__ __forceinline__ unsigned short f2bf(float f) {
  unsigned int u = __float_as_uint(f);
  u += 0x7fffu + ((u >> 16) & 1u);  // round-to-nearest-even
  return (unsigned short)(u >> 16);
}

// ---------------------------------------------------------------------------
// prep_x: wave-per-row over x. Converts to bf16 (row-major, same layout),
// writes nx2[row], atomically accumulates sum_x[128] and sum_nx2.
// ---------------------------------------------------------------------------
__global__ void prep_x(const float* __restrict__ x, unsigned short* __restrict__ xb,
                       float* __restrict__ nx2, float* __restrict__ sum_x,
                       float* __restrict__ sum_nx2, int N) {
  const int lane = threadIdx.x & 63;
  const int wave = threadIdx.x >> 6;
  const int gw = blockIdx.x * 4 + wave;
  const int nw = gridDim.x * 4;
  float c0 = 0.f, c1 = 0.f, s2 = 0.f;
  for (int row = gw; row < N; row += nw) {
    float v0 = x[row * D_DIM + lane];
    float v1 = x[row * D_DIM + 64 + lane];
    xb[row * D_DIM + lane] = f2bf(v0);
    xb[row * D_DIM + 64 + lane] = f2bf(v1);
    c0 += v0;
    c1 += v1;
    float sq = fmaf(v0, v0, v1 * v1);
#pragma unroll
    for (int off = 32; off; off >>= 1) sq += __shfl_down(sq, off);
    if (lane == 0) {
      nx2[row] = sq;
      s2 += sq;
    }
  }
  if (lane == 0) atomicAdd(sum_nx2, s2);
  __shared__ float cs[128];
  if (threadIdx.x < 128) cs[threadIdx.x] = 0.f;
  __syncthreads();
  atomicAdd(&cs[lane], c0);
  atomicAdd(&cs[lane + 64], c1);
  __syncthreads();
  if (threadIdx.x < 128) atomicAdd(&sum_x[threadIdx.x], cs[threadIdx.x]);
}

// ---------------------------------------------------------------------------
// prep_p: wave-per-row over p. Converts to bf16 and packs the per-column
// epilogue constants into colc[j] = (1+np2, np2, 1/(||p||*sqrt(ssd)), psi).
// ---------------------------------------------------------------------------
__global__ void prep_p(const float* __restrict__ p, unsigned short* __restrict__ pb,
                       const float* __restrict__ sum_x, const float* __restrict__ sum_nx2,
                       float4* __restrict__ colc, int M, int N) {
  const int lane = threadIdx.x & 63;
  const int wave = threadIdx.x >> 6;
  const int j = blockIdx.x * 4 + wave;
  if (j >= M) return;
  float p0 = p[j * D_DIM + lane];
  float p1 = p[j * D_DIM + 64 + lane];
  pb[j * D_DIM + lane] = f2bf(p0);
  pb[j * D_DIM + 64 + lane] = f2bf(p1);
  float np2 = fmaf(p0, p0, p1 * p1);
  float sd = fmaf(p0, sum_x[lane], p1 * sum_x[lane + 64]);
#pragma unroll
  for (int off = 32; off; off >>= 1) {
    np2 += __shfl_down(np2, off);
    sd += __shfl_down(sd, off);
  }
  if (lane == 0) {
    float ssd = *sum_nx2 + (float)N * np2 - 2.f * sd;
    float npn = sqrtf(np2);
    float4 cc;
    cc.x = 1.f + np2;
    cc.y = np2;
    cc.z = 1.f / (npn * sqrtf(ssd));
    cc.w = asinf(KCONST * (1.f - np2) / npn);
    colc[j] = cc;
  }
}

// ---------------------------------------------------------------------------
// pair_mfma: 64x64 output tile per block (4 waves; wave w owns 16 cols).
// Whole K=128 staged once in LDS (bf16), 4 k-steps of mfma_f32_16x16x32_bf16.
// Fused epilogue on C-fragment layout (col = lane&15 -> one column/lane).
// Per-block partial -> atomicAdd(out, partial/N).
// ---------------------------------------------------------------------------
__global__ __launch_bounds__(256, 4) void pair_mfma(
    const unsigned short* __restrict__ xb, const unsigned short* __restrict__ pb,
    const int* __restrict__ labels, const float* __restrict__ nx2,
    const float4* __restrict__ colc, float* __restrict__ out, float invN) {
  __shared__ float4 xs4[64 * 17];  // 64 rows x 128 bf16, padded stride 17 quads
  __shared__ float4 ps4[64 * 17];
  __shared__ float nxs[64];
  __shared__ int lbs[64];
  __shared__ float wred[4];

  const int tid = threadIdx.x;
  const int row0 = blockIdx.y * 64;
  const int col0 = blockIdx.x * 64;

  const float4* xg = (const float4*)(xb + (size_t)row0 * D_DIM);
  const float4* pg = (const float4*)(pb + (size_t)col0 * D_DIM);
#pragma unroll
  for (int t = 0; t < 4; ++t) {
    int i = tid + t * 256;
    int r = i >> 4, qq = i & 15;
    xs4[r * 17 + qq] = xg[r * 16 + qq];
    ps4[r * 17 + qq] = pg[r * 16 + qq];
  }
  if (tid < 64) {
    nxs[tid] = nx2[row0 + tid];
    lbs[tid] = labels[row0 + tid];
  }
  __syncthreads();

  const int m = tid & 15;        // non-K fragment index
  const int q = (tid >> 4) & 3;  // quad within wave
  const int w = tid >> 6;        // wave id

  f32x4 acc[4] = {(f32x4)(0.f), (f32x4)(0.f), (f32x4)(0.f), (f32x4)(0.f)};
#pragma unroll
  for (int s = 0; s < 4; ++s) {
    bf16x8 b = __builtin_bit_cast(bf16x8, ps4[(w * 16 + m) * 17 + s * 4 + q]);
#pragma unroll
    for (int r = 0; r < 4; ++r) {
      bf16x8 a = __builtin_bit_cast(bf16x8, xs4[(r * 16 + m) * 17 + s * 4 + q]);
      acc[r] = __builtin_amdgcn_mfma_f32_16x16x32_bf16(a, b, acc[r], 0, 0, 0);
    }
  }

  // ---- fused epilogue ----
  const int col = col0 + w * 16 + m;
  const float4 cc = colc[col];  // (1+np2, np2, cfi, psi)
  float ssum = 0.f;
#pragma unroll
  for (int r = 0; r < 4; ++r) {
#pragma unroll
    for (int g = 0; g < 4; ++g) {
      int lrow = r * 16 + q * 4 + g;
      float rn = nxs[lrow];
      int lb = lbs[lrow];
      float dot = acc[r][g];
      float num = fmaf(dot, cc.x, -cc.y * (1.f + rn));
      float den2 = fmaf(cc.y, rn, 1.f) - 2.f * dot;
      float u = num * cc.z * __builtin_amdgcn_rsqf(den2);
      u = fminf(1.f, fmaxf(-1.f, u));
      // branchless acos: |err| ~ 2e-8 (A&S 4.4.46 form)
      float ax = fabsf(u);
      float rt = __builtin_amdgcn_sqrtf(1.f - ax);
      float poly = fmaf(
          fmaf(fmaf(fmaf(fmaf(fmaf(fmaf(-0.0012624911f, ax, 0.0066700901f), ax,
                                   -0.0170881256f),
                              ax, 0.0308918810f),
                         ax, -0.0501743046f),
                    ax, 0.0889789874f),
               ax, -0.2145988016f),
          ax, 1.5707963050f);
      float ac = rt * poly;
      ac = (u >= 0.f) ? ac : 3.14159265358979f - ac;
      float ang = ac - cc.w;
      float a = fmaxf(0.f, ang);
      ssum += (col == lb) ? a : fmaxf(0.f, GAMMA_C - a);
    }
  }

#pragma unroll
  for (int off = 32; off; off >>= 1) ssum += __shfl_down(ssum, off);
  if ((tid & 63) == 0) wred[w] = ssum;
  __syncthreads();
  if (tid == 0) atomicAdd(out, (wred[0] + wred[1] + wred[2] + wred[3]) * invN);
}

extern "C" void kernel_launch(void* const* d_in, const int* in_sizes, int n_in,
                              void* d_out, int out_size, void* d_ws, size_t ws_size,
                              hipStream_t stream) {
  const float* x = (const float*)d_in[0];
  const float* p = (const float*)d_in[1];
  const int* labels = (const int*)d_in[2];
  float* out = (float*)d_out;
  const int N = in_sizes[2];          // 16384
  const int M = in_sizes[1] / D_DIM;  // 2048

  float* ws = (float*)d_ws;
  float* sum_x = ws;                        // 128
  float* sum_nx2 = ws + 128;                // 1 (zeroed region: 256 floats)
  float* nx2 = ws + 256;                    // N
  float4* colc = (float4*)(ws + 256 + N);   // M float4
  unsigned short* xb = (unsigned short*)(ws + 256 + N + 4 * M);        // N*128
  unsigned short* pb = (unsigned short*)(ws + 256 + N + 4 * M + 64 * N);  // M*128

  hipMemsetAsync(d_ws, 0, 256 * sizeof(float), stream);
  hipMemsetAsync(d_out, 0, sizeof(float), stream);

  prep_x<<<1024, 256, 0, stream>>>(x, xb, nx2, sum_x, sum_nx2, N);
  prep_p<<<M / 4, 256, 0, stream>>>(p, pb, sum_x, sum_nx2, colc, M, N);

  dim3 grid(M / 64, N / 64);
  pair_mfma<<<grid, 256, 0, stream>>>(xb, pb, labels, nx2, colc, out,
                                      1.0f / (float)N);
}

// Round 3
// 122.625 us; speedup vs baseline: 2.1410x; 1.8759x over previous
//
#include <hip/hip_runtime.h>
#include <math.h>

#define KCONST 0.1f
#define GAMMA_C 1.0f
#define D_DIM 128

typedef __attribute__((ext_vector_type(8))) short bf16x8;
typedef __attribute__((ext_vector_type(4))) float f32x4;

__device__ __forceinline__ unsigned short f2bf(float f) {
  unsigned int u = __float_as_uint(f);
  u += 0x7fffu + ((u >> 16) & 1u);  // round-to-nearest-even
  return (unsigned short)(u >> 16);
}

// ---------------------------------------------------------------------------
// prep_x: 128 blocks (hierarchical reduction: LDS first, ONE global atomic
// per address per block -> 128 serialized RMWs/address, not 1024).
// Converts x to bf16, writes nx2[row], accumulates sum_x[128], sum_nx2.
// Block 0 thread 0 also zeroes d_out (runs before pair_mfma in stream order).
// ---------------------------------------------------------------------------
__global__ void prep_x(const float* __restrict__ x, unsigned short* __restrict__ xb,
                       float* __restrict__ nx2, float* __restrict__ sum_x,
                       float* __restrict__ sum_nx2, float* __restrict__ out_zero,
                       int N) {
  if (blockIdx.x == 0 && threadIdx.x == 0) *out_zero = 0.f;
  const int lane = threadIdx.x & 63;
  const int wave = threadIdx.x >> 6;
  const int gw = blockIdx.x * 4 + wave;
  const int nw = gridDim.x * 4;
  const float2* x2 = (const float2*)x;
  ushort2* xb2 = (ushort2*)xb;
  float c0 = 0.f, c1 = 0.f, s2 = 0.f;
  for (int row = gw; row < N; row += nw) {
    float2 v = x2[row * 64 + lane];
    ushort2 b;
    b.x = f2bf(v.x);
    b.y = f2bf(v.y);
    xb2[row * 64 + lane] = b;
    c0 += v.x;
    c1 += v.y;
    float sq = fmaf(v.x, v.x, v.y * v.y);
#pragma unroll
    for (int off = 32; off; off >>= 1) sq += __shfl_down(sq, off);
    if (lane == 0) {
      nx2[row] = sq;
      s2 += sq;
    }
  }
  __shared__ float cs[128];
  __shared__ float s2s[4];
  if (threadIdx.x < 128) cs[threadIdx.x] = 0.f;
  __syncthreads();
  atomicAdd(&cs[2 * lane], c0);
  atomicAdd(&cs[2 * lane + 1], c1);
  if (lane == 0) s2s[wave] = s2;
  __syncthreads();
  if (threadIdx.x < 128) atomicAdd(&sum_x[threadIdx.x], cs[threadIdx.x]);
  if (threadIdx.x == 0)
    atomicAdd(sum_nx2, s2s[0] + s2s[1] + s2s[2] + s2s[3]);
}

// ---------------------------------------------------------------------------
// prep_p: wave-per-row. Converts p to bf16, packs per-column constants
// colc[j] = (1+np2, np2, 1/(||p||*sqrt(ssd)), psi).
// ---------------------------------------------------------------------------
__global__ void prep_p(const float* __restrict__ p, unsigned short* __restrict__ pb,
                       const float* __restrict__ sum_x, const float* __restrict__ sum_nx2,
                       float4* __restrict__ colc, int M, int N) {
  const int lane = threadIdx.x & 63;
  const int wave = threadIdx.x >> 6;
  const int j = blockIdx.x * 4 + wave;
  if (j >= M) return;
  const float2* p2 = (const float2*)p;
  ushort2* pb2 = (ushort2*)pb;
  float2 v = p2[j * 64 + lane];
  ushort2 b;
  b.x = f2bf(v.x);
  b.y = f2bf(v.y);
  pb2[j * 64 + lane] = b;
  float np2 = fmaf(v.x, v.x, v.y * v.y);
  float sd = fmaf(v.x, sum_x[2 * lane], v.y * sum_x[2 * lane + 1]);
#pragma unroll
  for (int off = 32; off; off >>= 1) {
    np2 += __shfl_down(np2, off);
    sd += __shfl_down(sd, off);
  }
  if (lane == 0) {
    float ssd = *sum_nx2 + (float)N * np2 - 2.f * sd;
    float npn = sqrtf(np2);
    float4 cc;
    cc.x = 1.f + np2;
    cc.y = np2;
    cc.z = 1.f / (npn * sqrtf(ssd));
    cc.w = asinf(KCONST * (1.f - np2) / npn);
    colc[j] = cc;
  }
}

// ---------------------------------------------------------------------------
// pair_mfma: 128x128 output tile per block (grid 2048). 4 waves; wave w owns
// 32 cols (2 col-frags), all 128 rows (8 row-frags) -> 64 MFMA/wave.
// K=128 staged once in padded LDS (stride 17 quads -> uniform bank groups).
// Fused epilogue on C-layout (col = lane&15), degree-3 acos poly.
// ---------------------------------------------------------------------------
__global__ __launch_bounds__(256, 2) void pair_mfma(
    const unsigned short* __restrict__ xb, const unsigned short* __restrict__ pb,
    const int* __restrict__ labels, const float* __restrict__ nx2,
    const float4* __restrict__ colc, float* __restrict__ out, float invN) {
  __shared__ float4 xs4[128 * 17];  // 128 rows x 16 quads, pad to 17
  __shared__ float4 ps4[128 * 17];
  __shared__ float nxs[128];
  __shared__ int lbs[128];
  __shared__ float wred[4];

  const int tid = threadIdx.x;
  const int row0 = blockIdx.y * 128;
  const int col0 = blockIdx.x * 128;

  const float4* xg = (const float4*)(xb + (size_t)row0 * D_DIM);
  const float4* pg = (const float4*)(pb + (size_t)col0 * D_DIM);
#pragma unroll
  for (int t = 0; t < 8; ++t) {
    int i = tid + t * 256;
    int r = i >> 4, qq = i & 15;
    xs4[r * 17 + qq] = xg[r * 16 + qq];
    ps4[r * 17 + qq] = pg[r * 16 + qq];
  }
  if (tid < 128) {
    nxs[tid] = nx2[row0 + tid];
    lbs[tid] = labels[row0 + tid];
  }
  __syncthreads();

  const int m = tid & 15;
  const int q = (tid >> 4) & 3;
  const int w = tid >> 6;

  f32x4 acc[8][2];
#pragma unroll
  for (int r = 0; r < 8; ++r) {
    acc[r][0] = (f32x4)(0.f);
    acc[r][1] = (f32x4)(0.f);
  }

#pragma unroll
  for (int s = 0; s < 4; ++s) {
    bf16x8 b0 = __builtin_bit_cast(bf16x8, ps4[(w * 32 + m) * 17 + s * 4 + q]);
    bf16x8 b1 = __builtin_bit_cast(bf16x8, ps4[(w * 32 + 16 + m) * 17 + s * 4 + q]);
#pragma unroll
    for (int r = 0; r < 8; ++r) {
      bf16x8 a = __builtin_bit_cast(bf16x8, xs4[(r * 16 + m) * 17 + s * 4 + q]);
      acc[r][0] = __builtin_amdgcn_mfma_f32_16x16x32_bf16(a, b0, acc[r][0], 0, 0, 0);
      acc[r][1] = __builtin_amdgcn_mfma_f32_16x16x32_bf16(a, b1, acc[r][1], 0, 0, 0);
    }
  }

  // ---- fused epilogue ----
  float ssum = 0.f;
#pragma unroll
  for (int c = 0; c < 2; ++c) {
    const int col = col0 + w * 32 + c * 16 + m;
    const float4 cc = colc[col];          // (1+np2, np2, cfi, psi)
    const float Ac = cc.x * cc.z;         // (1+np2)*cfi
    const float Bc = cc.y * cc.z;         // np2*cfi
#pragma unroll
    for (int r = 0; r < 8; ++r) {
#pragma unroll
      for (int g = 0; g < 4; ++g) {
        int lrow = r * 16 + q * 4 + g;
        float rn = nxs[lrow];
        float dot = acc[r][c][g];
        float den2 = fmaf(cc.y, rn, 1.f) - 2.f * dot;
        float nump = fmaf(dot, Ac, -Bc * (1.f + rn));
        float u = nump * __builtin_amdgcn_rsqf(den2);
        u = fminf(1.f, fmaxf(-1.f, u));
        // acos, A&S 4.4.45 degree-3: |err| <= 6.7e-5
        float ax = fabsf(u);
        float rt = __builtin_amdgcn_sqrtf(1.f - ax);
        float poly = fmaf(fmaf(fmaf(-0.0187293f, ax, 0.0742610f), ax,
                               -0.2121144f),
                          ax, 1.5707288f);
        float ac = rt * poly;
        ac = (u >= 0.f) ? ac : 3.14159265358979f - ac;
        float a = fmaxf(0.f, ac - cc.w);
        ssum += (col == lbs[lrow]) ? a : fmaxf(0.f, GAMMA_C - a);
      }
    }
  }

#pragma unroll
  for (int off = 32; off; off >>= 1) ssum += __shfl_down(ssum, off);
  if ((tid & 63) == 0) wred[w] = ssum;
  __syncthreads();
  if (tid == 0) atomicAdd(out, (wred[0] + wred[1] + wred[2] + wred[3]) * invN);
}

extern "C" void kernel_launch(void* const* d_in, const int* in_sizes, int n_in,
                              void* d_out, int out_size, void* d_ws, size_t ws_size,
                              hipStream_t stream) {
  const float* x = (const float*)d_in[0];
  const float* p = (const float*)d_in[1];
  const int* labels = (const int*)d_in[2];
  float* out = (float*)d_out;
  const int N = in_sizes[2];          // 16384
  const int M = in_sizes[1] / D_DIM;  // 2048

  float* ws = (float*)d_ws;
  float* sum_x = ws;                        // 128
  float* sum_nx2 = ws + 128;                // 1 (zeroed region: 256 floats)
  float* nx2 = ws + 256;                    // N
  float4* colc = (float4*)(ws + 256 + N);   // M float4
  unsigned short* xb = (unsigned short*)(ws + 256 + N + 4 * M);           // N*128
  unsigned short* pb = (unsigned short*)(ws + 256 + N + 4 * M + 64 * N);  // M*128

  hipMemsetAsync(d_ws, 0, 256 * sizeof(float), stream);

  prep_x<<<128, 256, 0, stream>>>(x, xb, nx2, sum_x, sum_nx2, out, N);
  prep_p<<<M / 4, 256, 0, stream>>>(p, pb, sum_x, sum_nx2, colc, M, N);

  dim3 grid(M / 128, N / 128);
  pair_mfma<<<grid, 256, 0, stream>>>(xb, pb, labels, nx2, colc, out,
                                      1.0f / (float)N);
}